// Round 7
// baseline (186.372 us; speedup 1.0000x reference)
//
#include <hip/hip_runtime.h>
#include <cstdint>

#define NN 16000
#define KK 16
#define FIN 32
#define HH 64
#define NE (NN*KK)
#define GG 64
#define NCELL (GG*GG)
#define KNNB 500            // NN*8/256
#define G1B  1000           // NN*16/256

// ---------------------------------------------------------------- prep + count
// pack[i] = (x, y, sq, idx) with sq = round(x^2)+round(y^2) UNFUSED (np c*c + sum).
// cnt[] must be zeroed beforehand (hipMemsetAsync). gmm init here (atomics on it
// only start in knn, several launches later).
__global__ __launch_bounds__(256) void prep_count_kernel(const float* __restrict__ c,
                                                         float4* __restrict__ pack,
                                                         unsigned* __restrict__ cellid,
                                                         unsigned* __restrict__ cnt,
                                                         unsigned* __restrict__ gmm) {
#pragma clang fp contract(off)
  int i = blockIdx.x * 256 + threadIdx.x;
  if (i == 0) { gmm[0] = 0x7F800000u; gmm[1] = 0u; }  // min=+inf bits, max=0 (d>=0)
  if (i >= NN) return;
  float xv = c[2*i], yv = c[2*i+1];
  float xx = xv * xv;            // round(x^2)  (no fma: contract off)
  float yy = yv * yv;            // round(y^2)
  float sq = xx + yy;            // round(xx+yy)
  pack[i] = make_float4(xv, yv, sq, __uint_as_float((unsigned)i));
  int cx = (int)(xv * GG); cx = cx > GG-1 ? GG-1 : (cx < 0 ? 0 : cx);
  int cy = (int)(yv * GG); cy = cy > GG-1 ? GG-1 : (cy < 0 ? 0 : cy);
  unsigned cell = (unsigned)(cy * GG + cx);
  cellid[i] = cell;
  atomicAdd(&cnt[cell], 1u);
}

// ---------------------------------------------------------------- prefix scan (single block, wave-shuffle)
__global__ __launch_bounds__(1024) void scan_kernel(const unsigned* __restrict__ cnt,
                                                    unsigned* __restrict__ cstart,
                                                    unsigned* __restrict__ cursor) {
  __shared__ unsigned wsum[16];
  int tid = threadIdx.x;
  int lane = tid & 63, wv = tid >> 6;
  unsigned c0 = cnt[tid*4+0], c1 = cnt[tid*4+1], c2 = cnt[tid*4+2], c3 = cnt[tid*4+3];
  unsigned s = c0 + c1 + c2 + c3;
  unsigned v = s;
#pragma unroll
  for (int off = 1; off < 64; off <<= 1) {         // inclusive wave scan
    unsigned u = __shfl_up(v, off, 64);
    if (lane >= off) v += u;
  }
  if (lane == 63) wsum[wv] = v;
  __syncthreads();
  if (wv == 0) {                                   // scan the 16 wave totals
    unsigned t = (lane < 16) ? wsum[lane] : 0u;
    unsigned vv = t;
#pragma unroll
    for (int off = 1; off < 16; off <<= 1) {
      unsigned u = __shfl_up(vv, off, 64);
      if (lane >= off) vv += u;
    }
    if (lane < 16) wsum[lane] = vv - t;            // exclusive
  }
  __syncthreads();
  unsigned b = wsum[wv] + v - s;                   // exclusive prefix of this thread's 4 cells
  cstart[tid*4+0] = b; cursor[tid*4+0] = b; b += c0;
  cstart[tid*4+1] = b; cursor[tid*4+1] = b; b += c1;
  cstart[tid*4+2] = b; cursor[tid*4+2] = b; b += c2;
  cstart[tid*4+3] = b; cursor[tid*4+3] = b; b += c3;
  if (tid == 1023) cstart[NCELL] = b;              // == NN
}

// ---------------------------------------------------------------- scatter into cell order
__global__ __launch_bounds__(256) void scatter_kernel(const float4* __restrict__ pack,
                                                      const unsigned* __restrict__ cellid,
                                                      unsigned* __restrict__ cursor,
                                                      float4* __restrict__ sorted,
                                                      int* __restrict__ sid) {
  int i = blockIdx.x * 256 + threadIdx.x;
  if (i >= NN) return;
  unsigned p = atomicAdd(&cursor[cellid[i]], 1u);
  sorted[p] = pack[i];                             // .w carries original index bits
  sid[p] = i;
}

// ---------------------------------------------------------------- knn (8 lanes/node) + edge epilogue, fused with gemm1
// knn d2 replicates the passing formula bit-exactly:
//   dot = fma(y_i,y_j, round(x_i*x_j)); d2 = round((sq_i+sq_j) - 2*dot)
// Key = map(d2bits)<<32 | j. Stop bound: union's 16th <= max over oct of kd[1]
// (8 lanes x first-2 = 16 elements <= that max). Merge: 16 rounds of oct-min.
// Epilogue computes edge d (direct form, same ops as before) + global min/max.
// Blocks >= KNNB run gemm1 (xw1 = x @ W1), independent work to fill the SIMDs.
__global__ __launch_bounds__(256) void knn_gemm1_kernel(const float4* __restrict__ sorted,
                                                        const unsigned* __restrict__ cstart,
                                                        const float* __restrict__ c,
                                                        int* __restrict__ nbr,
                                                        float* __restrict__ de,
                                                        unsigned* __restrict__ gmm,
                                                        const float* __restrict__ x,
                                                        const float* __restrict__ w1,
                                                        float* __restrict__ xw) {
#pragma clang fp contract(off)
  if (blockIdx.x >= KNNB) {
    // ---------------- gemm1: thread = (row i, feature quad fq), KIN=32
    int gid = (int)(blockIdx.x - KNNB) * 256 + threadIdx.x;   // 0..255999
    int i = gid >> 4, fq = gid & 15;
    const float4* ar = (const float4*)(x + i * FIN);
    float4 A[FIN/4];
#pragma unroll
    for (int q = 0; q < FIN/4; ++q) A[q] = ar[q];
    float4 acc = make_float4(0.f, 0.f, 0.f, 0.f);
#pragma unroll
    for (int k = 0; k < FIN; ++k) {
      float av = ((const float*)A)[k];
      float4 wv4 = *(const float4*)(w1 + k*HH + 4*fq);
      acc.x = fmaf(av, wv4.x, acc.x);
      acc.y = fmaf(av, wv4.y, acc.y);
      acc.z = fmaf(av, wv4.z, acc.z);
      acc.w = fmaf(av, wv4.w, acc.w);
    }
    *(float4*)(xw + i*HH + 4*fq) = acc;
    return;
  }
  // ---------------- knn: 8 lanes per node
  int g = blockIdx.x * 256 + threadIdx.x;
  int t = g >> 3;                                // sorted node index
  int q = g & 7;                                 // oct lane
  const float4 me = sorted[t];
  const int myid = (int)__float_as_uint(me.w);
  const float h = 1.0f / GG;                     // exact (2^-6)
  int cx = (int)(me.x * GG); cx = cx > GG-1 ? GG-1 : (cx < 0 ? 0 : cx);
  int cy = (int)(me.y * GG); cy = cy > GG-1 ? GG-1 : (cy < 0 ? 0 : cy);

  unsigned long long kd[KK];
#pragma unroll
  for (int m = 0; m < KK; ++m) kd[m] = ~0ull;

  auto scan_cells = [&](int row, int x0, int x1) {
    if (row < 0 || row >= GG) return;
    x0 = x0 < 0 ? 0 : x0;
    x1 = x1 > GG-1 ? GG-1 : x1;
    if (x0 > x1) return;
    unsigned p  = cstart[row*GG + x0];
    unsigned pe = cstart[row*GG + x1 + 1];
    for (unsigned pp = p + (unsigned)q; pp < pe; pp += 8) {
      float4 pj = sorted[pp];
      int j = (int)__float_as_uint(pj.w);
      float xprod = me.x * pj.x;                      // round(x_i*x_j)
      float dot   = __builtin_fmaf(me.y, pj.y, xprod);
      float S     = me.z + pj.z;                      // round(sq_i+sq_j)
      float twod  = dot + dot;                        // exact *2
      float d2    = S - twod;                         // one rounding
      unsigned ub = __float_as_uint(d2);
      ub = (ub & 0x80000000u) ? ~ub : (ub | 0x80000000u);   // total-order map
      unsigned long long key = ((unsigned long long)ub << 32) | (unsigned)j;
      if (j != myid && key < kd[KK-1]) {
        unsigned long long ck = key;
#pragma unroll
        for (int m = 0; m < KK; ++m) {
          bool sw = ck < kd[m];
          unsigned long long lo = sw ? ck : kd[m];
          unsigned long long hi = sw ? kd[m] : ck;
          kd[m] = lo; ck = hi;
        }
      }
    }
  };

  int R = 2;
  for (int dy = -R; dy <= R; ++dy) scan_cells(cy + dy, cx - R, cx + R);

  while (true) {
    bool whole = (cx - R <= 0) && (cx + R >= GG-1) && (cy - R <= 0) && (cy + R >= GG-1);
    if (whole) break;                               // everything scanned
    // union's 16th smallest <= max over oct of per-lane kd[1]
    unsigned long long b16 = kd[1];
    unsigned long long o1 = __shfl_xor(b16, 1, 64); b16 = o1 > b16 ? o1 : b16;
    unsigned long long o2 = __shfl_xor(b16, 2, 64); b16 = o2 > b16 ? o2 : b16;
    unsigned long long o4 = __shfl_xor(b16, 4, 64); b16 = o4 > b16 ? o4 : b16;
    if (b16 != ~0ull) {
      float edge = 1e30f;
      if (cx - R > 0)    edge = fminf(edge, me.x - (float)(cx - R) * h);
      if (cx + R < GG-1) edge = fminf(edge, (float)(cx + R + 1) * h - me.x);
      if (cy - R > 0)    edge = fminf(edge, me.y - (float)(cy - R) * h);
      if (cy + R < GG-1) edge = fminf(edge, (float)(cy + R + 1) * h - me.y);
      float lim = edge * edge - 1e-5f;              // margin >> Gram noise (~1e-6)
      if (lim > 0.0f) {
        unsigned lb = __float_as_uint(lim) | 0x80000000u;   // map(lim), lim>0
        if ((unsigned)(b16 >> 32) <= lb) break;
      }
    }
    ++R;
    scan_cells(cy - R, cx - R, cx + R);             // new perimeter
    scan_cells(cy + R, cx - R, cx + R);
    for (int dy = -(R-1); dy <= R-1; ++dy) {
      scan_cells(cy + dy, cx - R, cx - R);
      scan_cells(cy + dy, cx + R, cx + R);
    }
  }

  // merge 8 sorted per-lane lists -> global top-16 (keys unique via j bits)
  unsigned res[2];
  for (int r = 0; r < KK; ++r) {
    unsigned long long md = kd[0];
    unsigned long long o1 = __shfl_xor(md, 1, 64); md = o1 < md ? o1 : md;
    unsigned long long o2 = __shfl_xor(md, 2, 64); md = o2 < md ? o2 : md;
    unsigned long long o4 = __shfl_xor(md, 4, 64); md = o4 < md ? o4 : md;
    if (kd[0] == md) {                              // unique winner lane pops
#pragma unroll
      for (int m = 0; m < KK-1; ++m) kd[m] = kd[m+1];
      kd[KK-1] = ~0ull;
    }
    if ((r >> 1) == q) res[r & 1] = (unsigned)(md & 0xFFFFFFFFull);
  }
  int2 w2; w2.x = (int)res[0]; w2.y = (int)res[1];
  *(int2*)(nbr + myid*KK + 2*q) = w2;

  // ---------------- edge epilogue: d for the 2 owned neighbors (same ops as before)
  unsigned bmin = 0x7F800000u, bmax = 0u;
#pragma unroll
  for (int e = 0; e < 2; ++e) {
    int j = (int)res[e];
    float dx = me.x - c[2*j];
    float dy = me.y - c[2*j+1];
    float xx = dx * dx;
    float yy = dy * dy;
    float d  = __builtin_sqrtf(xx + yy);
    de[myid*KK + 2*q + e] = d;
    unsigned b = __float_as_uint(d);               // d >= 0: bit order == float order
    bmin = bmin < b ? bmin : b;
    bmax = bmax > b ? bmax : b;
  }
#pragma unroll
  for (int off = 32; off > 0; off >>= 1) {
    unsigned ob = __shfl_xor(bmin, off, 64);
    bmin = bmin < ob ? bmin : ob;
    unsigned oB = __shfl_xor(bmax, off, 64);
    bmax = bmax > oB ? bmax : oB;
  }
  if ((threadIdx.x & 63) == 0) {
    atomicMin(&gmm[0], bmin);
    atomicMax(&gmm[1], bmax);
  }
}

// ---------------------------------------------------------------- ew + deg + dis
__global__ __launch_bounds__(256) void ewdeg_kernel(const unsigned* __restrict__ gmm,
                                                    float* __restrict__ de,   // in: d, out: ew
                                                    float* __restrict__ dis) {
#pragma clang fp contract(off)
  int i = blockIdx.x * 256 + threadIdx.x;
  if (i >= NN) return;
  float mx  = __uint_as_float(gmm[1]);
  float rng = mx - __uint_as_float(gmm[0]);
  float deg = 0.0f;                         // edges first, self-loop last (segment_sum order)
  float4* dp = (float4*)(de + i*KK);
#pragma unroll
  for (int q = 0; q < 4; ++q) {
    float4 v = dp[q];
    float e0 = (mx - v.x) / rng;
    float e1 = (mx - v.y) / rng;
    float e2 = (mx - v.z) / rng;
    float e3 = (mx - v.w) / rng;
    deg = deg + e0; deg = deg + e1;
    deg = deg + e2; deg = deg + e3;
    dp[q] = make_float4(e0, e1, e2, e3);
  }
  deg = deg + 1.0f;                         // self-loop weight 1, added last
  dis[i] = 1.0f / __builtin_sqrtf(deg);     // deg >= 1
}

// ---------------------------------------------------------------- gemm2: xw2 = h1 @ W2, KIN=64, 4 features/thread
__global__ __launch_bounds__(256) void gemm2_kernel(const float* __restrict__ a,
                                                    const float* __restrict__ w,
                                                    float* __restrict__ o) {
  int gid = blockIdx.x * 256 + threadIdx.x;   // N*16 total
  int i = gid >> 4, fq = gid & 15;
  const float4* ar = (const float4*)(a + i * HH);
  float4 A[HH/4];
#pragma unroll
  for (int q = 0; q < HH/4; ++q) A[q] = ar[q];
  float4 acc = make_float4(0.f, 0.f, 0.f, 0.f);
#pragma unroll
  for (int k = 0; k < HH; ++k) {
    float av = ((const float*)A)[k];
    float4 wv4 = *(const float4*)(w + k*HH + 4*fq);
    acc.x = fmaf(av, wv4.x, acc.x);
    acc.y = fmaf(av, wv4.y, acc.y);
    acc.z = fmaf(av, wv4.z, acc.z);
    acc.w = fmaf(av, wv4.w, acc.w);
  }
  *(float4*)(o + i*HH + 4*fq) = acc;
}

// ---------------------------------------------------------------- aggregate + relu (layer 1 body)
// Iterates in spatially-sorted order (sid) for gather locality; per-node
// arithmetic identical to before -> bit-identical output.
__global__ __launch_bounds__(256) void agg_relu_kernel(const float* __restrict__ xw,
                                                       const int* __restrict__ nbr,
                                                       const float* __restrict__ ew,
                                                       const float* __restrict__ dis,
                                                       const float* __restrict__ b,
                                                       const int* __restrict__ sid,
                                                       float* __restrict__ h) {
  int wv = threadIdx.x >> 6, lane = threadIdx.x & 63;
  int i = sid[(blockIdx.x << 2) + wv];
  float di = dis[i];
  float acc = 0.0f;
#pragma unroll 4
  for (int k = 0; k < KK; ++k) {
    int s = nbr[i*KK + k];
    float coef = (dis[s] * ew[i*KK + k]) * di;   // (dis[s]*w)*dis[t]
    acc = fmaf(coef, xw[s*HH + lane], acc);
  }
  acc = fmaf(di * di, xw[i*HH + lane], acc);     // self loop last
  float v = acc + b[lane];
  h[i*HH + lane] = fmaxf(v, 0.0f);
}

// ---------------------------------------------------------------- aggregate + relu + fc (final)
__global__ __launch_bounds__(256) void agg_fc_kernel(const float* __restrict__ xw,
                                                     const int* __restrict__ nbr,
                                                     const float* __restrict__ ew,
                                                     const float* __restrict__ dis,
                                                     const float* __restrict__ b,
                                                     const float* __restrict__ wfc,
                                                     const float* __restrict__ bfc,
                                                     const int* __restrict__ sid,
                                                     float* __restrict__ out) {
  int wv = threadIdx.x >> 6, lane = threadIdx.x & 63;
  int i = sid[(blockIdx.x << 2) + wv];
  float di = dis[i];
  float acc = 0.0f;
#pragma unroll 4
  for (int k = 0; k < KK; ++k) {
    int s = nbr[i*KK + k];
    float coef = (dis[s] * ew[i*KK + k]) * di;
    acc = fmaf(coef, xw[s*HH + lane], acc);
  }
  acc = fmaf(di * di, xw[i*HH + lane], acc);
  float v = fmaxf(acc + b[lane], 0.0f);             // h2 feature
  float p = v * wfc[lane];                          // h2 @ Wfc  (F_OUT = 1)
#pragma unroll
  for (int off = 32; off > 0; off >>= 1) p = p + __shfl_xor(p, off, 64);
  if (lane == 0) out[i] = p + bfc[0];
}

// ---------------------------------------------------------------- launch
extern "C" void kernel_launch(void* const* d_in, const int* in_sizes, int n_in,
                              void* d_out, int out_size, void* d_ws, size_t ws_size,
                              hipStream_t stream) {
  (void)in_sizes; (void)n_in; (void)out_size; (void)ws_size;
  const float* x   = (const float*)d_in[0];
  const float* c   = (const float*)d_in[1];
  const float* W1  = (const float*)d_in[2];
  const float* b1  = (const float*)d_in[3];
  const float* W2  = (const float*)d_in[4];
  const float* b2  = (const float*)d_in[5];
  const float* Wfc = (const float*)d_in[6];
  const float* bfc = (const float*)d_in[7];
  float* out = (float*)d_out;

  char* ws = (char*)d_ws;
  size_t off = 0;
  auto alloc = [&](size_t bytes) -> void* {
    void* p = ws + off;
    off += (bytes + 255) & ~size_t(255);
    return p;
  };
  float4*   pack   = (float4*)  alloc(NN * sizeof(float4));       // 256 KB
  float4*   sorted = (float4*)  alloc(NN * sizeof(float4));       // 256 KB
  unsigned* cnt    = (unsigned*)alloc(NCELL * sizeof(unsigned));  // 16 KB
  unsigned* cstart = (unsigned*)alloc((NCELL+1) * sizeof(unsigned));
  unsigned* cursor = (unsigned*)alloc(NCELL * sizeof(unsigned));
  unsigned* cellid = (unsigned*)alloc(NN * sizeof(unsigned));     // 64 KB
  int*      sid    = (int*)     alloc(NN * sizeof(int));          // 64 KB
  int*      nbr    = (int*)     alloc(NE * sizeof(int));          // 1 MB
  float*    ew     = (float*)   alloc(NE * sizeof(float));        // 1 MB (d then ew in-place)
  float*    dis    = (float*)   alloc(NN * sizeof(float));        // 64 KB
  unsigned* gmm    = (unsigned*)alloc(2 * sizeof(unsigned));
  float*    xw     = (float*)   alloc(NN * HH * sizeof(float));   // 4 MB (xw1, then xw2)
  float*    h1     = (float*)   alloc(NN * HH * sizeof(float));   // 4 MB

  const int NB = (NN + 255) / 256;
  hipMemsetAsync(cnt, 0, NCELL * sizeof(unsigned), stream);
  prep_count_kernel<<<NB,   256, 0, stream>>>(c, pack, cellid, cnt, gmm);
  scan_kernel      <<<1,   1024, 0, stream>>>(cnt, cstart, cursor);
  scatter_kernel   <<<NB,   256, 0, stream>>>(pack, cellid, cursor, sorted, sid);
  knn_gemm1_kernel <<<KNNB + G1B, 256, 0, stream>>>(sorted, cstart, c, nbr, ew, gmm, x, W1, xw);
  ewdeg_kernel     <<<NB,   256, 0, stream>>>(gmm, ew, dis);
  agg_relu_kernel  <<<NN/4, 256, 0, stream>>>(xw, nbr, ew, dis, b1, sid, h1);
  gemm2_kernel     <<<NN*16/256, 256, 0, stream>>>(h1, W2, xw);
  agg_fc_kernel    <<<NN/4, 256, 0, stream>>>(xw, nbr, ew, dis, b2, Wfc, bfc, sid, out);
}

// Round 8
// 183.295 us; speedup vs baseline: 1.0168x; 1.0168x over previous
//
#include <hip/hip_runtime.h>
#include <cstdint>

#define NN 16000
#define KK 16
#define FIN 32
#define HH 64
#define NE (NN*KK)
#define GG 64
#define NCELL (GG*GG)
#define BUFCAP 512

// ---------------------------------------------------------------- prep + count
__global__ __launch_bounds__(256) void prep_count_kernel(const float* __restrict__ c,
                                                         float4* __restrict__ pack,
                                                         unsigned* __restrict__ cellid,
                                                         unsigned* __restrict__ cnt,
                                                         unsigned* __restrict__ gmm) {
#pragma clang fp contract(off)
  int i = blockIdx.x * 256 + threadIdx.x;
  if (i == 0) { gmm[0] = 0x7F800000u; gmm[1] = 0u; }  // min=+inf bits, max=0 (d>=0)
  if (i >= NN) return;
  float xv = c[2*i], yv = c[2*i+1];
  float xx = xv * xv;            // round(x^2)  (no fma: contract off)
  float yy = yv * yv;            // round(y^2)
  float sq = xx + yy;            // round(xx+yy)
  pack[i] = make_float4(xv, yv, sq, __uint_as_float((unsigned)i));
  int cx = (int)(xv * GG); cx = cx > GG-1 ? GG-1 : (cx < 0 ? 0 : cx);
  int cy = (int)(yv * GG); cy = cy > GG-1 ? GG-1 : (cy < 0 ? 0 : cy);
  unsigned cell = (unsigned)(cy * GG + cx);
  cellid[i] = cell;
  atomicAdd(&cnt[cell], 1u);
}

// ---------------------------------------------------------------- prefix scan (single block, wave-shuffle)
__global__ __launch_bounds__(1024) void scan_kernel(const unsigned* __restrict__ cnt,
                                                    unsigned* __restrict__ cstart,
                                                    unsigned* __restrict__ cursor) {
  __shared__ unsigned wsum[16];
  int tid = threadIdx.x;
  int lane = tid & 63, wv = tid >> 6;
  unsigned c0 = cnt[tid*4+0], c1 = cnt[tid*4+1], c2 = cnt[tid*4+2], c3 = cnt[tid*4+3];
  unsigned s = c0 + c1 + c2 + c3;
  unsigned v = s;
#pragma unroll
  for (int off = 1; off < 64; off <<= 1) {
    unsigned u = __shfl_up(v, off, 64);
    if (lane >= off) v += u;
  }
  if (lane == 63) wsum[wv] = v;
  __syncthreads();
  if (wv == 0) {
    unsigned t = (lane < 16) ? wsum[lane] : 0u;
    unsigned vv = t;
#pragma unroll
    for (int off = 1; off < 16; off <<= 1) {
      unsigned u = __shfl_up(vv, off, 64);
      if (lane >= off) vv += u;
    }
    if (lane < 16) wsum[lane] = vv - t;            // exclusive
  }
  __syncthreads();
  unsigned b = wsum[wv] + v - s;
  cstart[tid*4+0] = b; cursor[tid*4+0] = b; b += c0;
  cstart[tid*4+1] = b; cursor[tid*4+1] = b; b += c1;
  cstart[tid*4+2] = b; cursor[tid*4+2] = b; b += c2;
  cstart[tid*4+3] = b; cursor[tid*4+3] = b; b += c3;
  if (tid == 1023) cstart[NCELL] = b;              // == NN
}

// ---------------------------------------------------------------- scatter into cell order
__global__ __launch_bounds__(256) void scatter_kernel(const float4* __restrict__ pack,
                                                      const unsigned* __restrict__ cellid,
                                                      unsigned* __restrict__ cursor,
                                                      float4* __restrict__ sorted,
                                                      int* __restrict__ sid) {
  int i = blockIdx.x * 256 + threadIdx.x;
  if (i >= NN) return;
  unsigned p = atomicAdd(&cursor[cellid[i]], 1u);
  sorted[p] = pack[i];                             // .w carries original index bits
  sid[p] = i;
}

// ---------------------------------------------------------------- knn: wave per 2x2-cell block, LDS-staged region
// d2 bit-exact vs passing rounds: dot = fma(y_i,y_j, round(x_i*x_j));
// d2 = round((sq_i+sq_j) - 2*dot). Key = map(d2bits)<<32 | j.
// 16 nodes/wave x 4 lanes; candidates staged once in LDS and reused by all nodes.
// Stop bound per node: quad-max of kd[3] (16 elements <= it) vs squared distance
// to staged-rect boundary minus 1e-5 margin (>> 1e-6 Gram noise) -> provably exact.
__global__ __launch_bounds__(64) void knn_kernel(const float4* __restrict__ sorted,
                                                 const unsigned* __restrict__ cstart,
                                                 const float* __restrict__ c,
                                                 int* __restrict__ nbr,
                                                 float* __restrict__ de,
                                                 unsigned* __restrict__ gmm) {
#pragma clang fp contract(off)
  __shared__ float4 buf[BUFCAP];                   // 8 KB
  const int lane = threadIdx.x;
  const int q = lane & 3;
  const int sx = blockIdx.x & 31, sy = blockIdx.x >> 5;
  const int cx0 = sx * 2, cy0 = sy * 2;
  const float h = 1.0f / GG;                       // exact 2^-6

  unsigned s0 = cstart[cy0*GG + cx0],       e0 = cstart[cy0*GG + cx0 + 2];
  unsigned s1 = cstart[(cy0+1)*GG + cx0],   e1 = cstart[(cy0+1)*GG + cx0 + 2];
  int len0 = (int)(e0 - s0);
  int B = len0 + (int)(e1 - s1);
  if (B == 0) return;

  // ---- stage initial 6x6 rect (clamped) into LDS
  int sxa = cx0-2 < 0 ? 0 : cx0-2;
  int sxb = cx0+3 > GG-1 ? GG-1 : cx0+3;
  int sya = cy0-2 < 0 ? 0 : cy0-2;
  int syb = cy0+3 > GG-1 ? GG-1 : cy0+3;
  int cnt = 0;
  bool hasBuf = true, frozen = false;
  {
    int tot = 0;
    for (int y = sya; y <= syb; ++y)
      tot += (int)(cstart[y*GG + sxb + 1] - cstart[y*GG + sxa]);
    if (tot > BUFCAP) { hasBuf = false; frozen = true; }
    else {
      for (int y = sya; y <= syb; ++y) {
        unsigned p0 = cstart[y*GG + sxa], p1 = cstart[y*GG + sxb + 1];
        for (unsigned p = p0 + (unsigned)lane; p < p1; p += 64)
          buf[cnt + (int)(p - p0)] = sorted[p];
        cnt += (int)(p1 - p0);
      }
    }
  }

  // ---- chunks of 16 nodes
  for (int cbase = 0; cbase < B; cbase += 16) {
    int nid = cbase + (lane >> 2);
    bool have = nid < B;
    float4 me = make_float4(2.f, 2.f, 8.f, 0.f);
    int myid = -1;
    if (have) {
      unsigned p = (nid < len0) ? (s0 + (unsigned)nid) : (s1 + (unsigned)(nid - len0));
      me = sorted[p];
      myid = (int)__float_as_uint(me.w);
    }
    unsigned long long kd[KK];
#pragma unroll
    for (int m = 0; m < KK; ++m) kd[m] = ~0ull;

    auto process = [&](float4 cand) {
      int j = (int)__float_as_uint(cand.w);
      float xprod = me.x * cand.x;                       // round(x_i*x_j)
      float dot   = __builtin_fmaf(me.y, cand.y, xprod); // BLAS K=2 fma
      float S     = me.z + cand.z;                       // round(sq_i+sq_j)
      float twod  = dot + dot;                           // exact *2
      float d2    = S - twod;                            // one rounding
      unsigned ub = __float_as_uint(d2);
      ub = (ub & 0x80000000u) ? ~ub : (ub | 0x80000000u);
      unsigned long long key = ((unsigned long long)ub << 32) | (unsigned)j;
      if (have && j != myid && key < kd[KK-1]) {
        unsigned long long ck = key;
#pragma unroll
        for (int m = 0; m < KK; ++m) {
          bool sw = ck < kd[m];
          unsigned long long lo = sw ? ck : kd[m];
          unsigned long long hi = sw ? kd[m] : ck;
          kd[m] = lo; ck = hi;
        }
      }
    };
    auto scanGlobalSpan = [&](unsigned p0, unsigned p1) {
      for (unsigned p = p0 + (unsigned)q; p < p1; p += 4) process(sorted[p]);
    };

    // local rect for this chunk
    int lxa, lxb, lya, lyb;
    if (hasBuf) {
      lxa = sxa; lxb = sxb; lya = sya; lyb = syb;
      for (int m = q; m < cnt; m += 4) process(buf[m]);
    } else {
      lxa = cx0-2 < 0 ? 0 : cx0-2;
      lxb = cx0+3 > GG-1 ? GG-1 : cx0+3;
      lya = cy0-2 < 0 ? 0 : cy0-2;
      lyb = cy0+3 > GG-1 ? GG-1 : cy0+3;
      for (int y = lya; y <= lyb; ++y)
        scanGlobalSpan(cstart[y*GG + lxa], cstart[y*GG + lxb + 1]);
    }

    // ---- ring expansion until provably done
    while (true) {
      unsigned long long b16 = kd[3];
      unsigned long long o1 = __shfl_xor(b16, 1, 64); b16 = o1 > b16 ? o1 : b16;
      unsigned long long o2 = __shfl_xor(b16, 2, 64); b16 = o2 > b16 ? o2 : b16;
      bool sat;
      if (!have) sat = true;
      else if (b16 == ~0ull) sat = false;
      else {
        float edge = 1e30f;
        if (lxa > 0)    edge = fminf(edge, me.x - (float)lxa * h);
        if (lxb < GG-1) edge = fminf(edge, (float)(lxb+1) * h - me.x);
        if (lya > 0)    edge = fminf(edge, me.y - (float)lya * h);
        if (lyb < GG-1) edge = fminf(edge, (float)(lyb+1) * h - me.y);
        float lim = edge * edge - 1e-5f;
        sat = (lim > 0.0f) &&
              ((unsigned)(b16 >> 32) <= (__float_as_uint(lim) | 0x80000000u));
      }
      bool whole = (lxa <= 0) && (lxb >= GG-1) && (lya <= 0) && (lyb >= GG-1);
      if (whole || !__any(!sat)) break;

      int nxa = lxa-1 < 0 ? 0 : lxa-1;
      int nxb = lxb+1 > GG-1 ? GG-1 : lxb+1;
      int nya = lya-1 < 0 ? 0 : lya-1;
      int nyb = lyb+1 > GG-1 ? GG-1 : lyb+1;
      // new-perimeter size
      int newN = 0;
      if (nya < lya) newN += (int)(cstart[nya*GG + nxb + 1] - cstart[nya*GG + nxa]);
      if (nyb > lyb) newN += (int)(cstart[nyb*GG + nxb + 1] - cstart[nyb*GG + nxa]);
      if (nxa < lxa) for (int y = lya; y <= lyb; ++y)
        newN += (int)(cstart[y*GG + nxa + 1] - cstart[y*GG + nxa]);
      if (nxb > lxb) for (int y = lya; y <= lyb; ++y)
        newN += (int)(cstart[y*GG + nxb + 1] - cstart[y*GG + nxb]);

      bool stage = hasBuf && !frozen && (cnt + newN <= BUFCAP);
      if (stage) {
        int cntOld = cnt;
        auto stageSpan = [&](unsigned p0, unsigned p1) {
          for (unsigned p = p0 + (unsigned)lane; p < p1; p += 64)
            buf[cnt + (int)(p - p0)] = sorted[p];
          cnt += (int)(p1 - p0);
        };
        if (nya < lya) stageSpan(cstart[nya*GG + nxa], cstart[nya*GG + nxb + 1]);
        if (nyb > lyb) stageSpan(cstart[nyb*GG + nxa], cstart[nyb*GG + nxb + 1]);
        if (nxa < lxa) for (int y = lya; y <= lyb; ++y)
          stageSpan(cstart[y*GG + nxa], cstart[y*GG + nxa + 1]);
        if (nxb > lxb) for (int y = lya; y <= lyb; ++y)
          stageSpan(cstart[y*GG + nxb], cstart[y*GG + nxb + 1]);
        for (int m = cntOld + q; m < cnt; m += 4) process(buf[m]);
        sxa = nxa; sxb = nxb; sya = nya; syb = nyb;   // staged rect grows
      } else {
        frozen = true;
        if (nya < lya) scanGlobalSpan(cstart[nya*GG + nxa], cstart[nya*GG + nxb + 1]);
        if (nyb > lyb) scanGlobalSpan(cstart[nyb*GG + nxa], cstart[nyb*GG + nxb + 1]);
        if (nxa < lxa) for (int y = lya; y <= lyb; ++y)
          scanGlobalSpan(cstart[y*GG + nxa], cstart[y*GG + nxa + 1]);
        if (nxb > lxb) for (int y = lya; y <= lyb; ++y)
          scanGlobalSpan(cstart[y*GG + nxb], cstart[y*GG + nxb + 1]);
      }
      lxa = nxa; lxb = nxb; lya = nya; lyb = nyb;
    }

    // ---- merge 4 sorted per-lane lists -> global top-16 (keys unique via j bits)
    unsigned res[4];
    for (int r = 0; r < KK; ++r) {
      unsigned long long md = kd[0];
      unsigned long long m1 = __shfl_xor(md, 1, 64); md = m1 < md ? m1 : md;
      unsigned long long m2 = __shfl_xor(md, 2, 64); md = m2 < md ? m2 : md;
      if (kd[0] == md) {
#pragma unroll
        for (int m = 0; m < KK-1; ++m) kd[m] = kd[m+1];
        kd[KK-1] = ~0ull;
      }
      if ((r >> 2) == q) res[r & 3] = (unsigned)(md & 0xFFFFFFFFull);
    }

    // ---- write nbr + edge epilogue (identical ops to passing rounds)
    unsigned bmin = 0xFFFFFFFFu, bmax = 0u;
    if (have) {
      int4 w4; w4.x = (int)res[0]; w4.y = (int)res[1]; w4.z = (int)res[2]; w4.w = (int)res[3];
      *(int4*)(nbr + myid*KK + 4*q) = w4;
#pragma unroll
      for (int e = 0; e < 4; ++e) {
        int j = (int)res[e];
        float dx = me.x - c[2*j];
        float dy = me.y - c[2*j+1];
        float xx = dx * dx;
        float yy = dy * dy;
        float d  = __builtin_sqrtf(xx + yy);
        de[myid*KK + 4*q + e] = d;
        unsigned bb = __float_as_uint(d);
        bmin = bmin < bb ? bmin : bb;
        bmax = bmax > bb ? bmax : bb;
      }
    }
#pragma unroll
    for (int off = 32; off > 0; off >>= 1) {
      unsigned ob = __shfl_xor(bmin, off, 64);
      bmin = bmin < ob ? bmin : ob;
      unsigned oB = __shfl_xor(bmax, off, 64);
      bmax = bmax > oB ? bmax : oB;
    }
    if (lane == 0) {
      atomicMin(&gmm[0], bmin);
      atomicMax(&gmm[1], bmax);
    }
  }
}

// ---------------------------------------------------------------- ew + deg + dis
__global__ __launch_bounds__(256) void ewdeg_kernel(const unsigned* __restrict__ gmm,
                                                    float* __restrict__ de,   // in: d, out: ew
                                                    float* __restrict__ dis) {
#pragma clang fp contract(off)
  int i = blockIdx.x * 256 + threadIdx.x;
  if (i >= NN) return;
  float mx  = __uint_as_float(gmm[1]);
  float rng = mx - __uint_as_float(gmm[0]);
  float deg = 0.0f;                         // edges first, self-loop last (segment_sum order)
  float4* dp = (float4*)(de + i*KK);
#pragma unroll
  for (int qq = 0; qq < 4; ++qq) {
    float4 v = dp[qq];
    float e0 = (mx - v.x) / rng;
    float e1 = (mx - v.y) / rng;
    float e2 = (mx - v.z) / rng;
    float e3 = (mx - v.w) / rng;
    deg = deg + e0; deg = deg + e1;
    deg = deg + e2; deg = deg + e3;
    dp[qq] = make_float4(e0, e1, e2, e3);
  }
  deg = deg + 1.0f;                         // self-loop weight 1, added last
  dis[i] = 1.0f / __builtin_sqrtf(deg);     // deg >= 1
}

// ---------------------------------------------------------------- gemm1: xw1 = x @ W1, KIN=32, 4 features/thread
__global__ __launch_bounds__(256) void gemm1_kernel(const float* __restrict__ a,
                                                    const float* __restrict__ w,
                                                    float* __restrict__ o) {
  int gid = blockIdx.x * 256 + threadIdx.x;   // N*16 total
  int i = gid >> 4, fq = gid & 15;
  const float4* ar = (const float4*)(a + i * FIN);
  float4 A[FIN/4];
#pragma unroll
  for (int qq = 0; qq < FIN/4; ++qq) A[qq] = ar[qq];
  float4 acc = make_float4(0.f, 0.f, 0.f, 0.f);
#pragma unroll
  for (int k = 0; k < FIN; ++k) {
    float av = ((const float*)A)[k];
    float4 wv4 = *(const float4*)(w + k*HH + 4*fq);
    acc.x = fmaf(av, wv4.x, acc.x);
    acc.y = fmaf(av, wv4.y, acc.y);
    acc.z = fmaf(av, wv4.z, acc.z);
    acc.w = fmaf(av, wv4.w, acc.w);
  }
  *(float4*)(o + i*HH + 4*fq) = acc;
}

// ---------------------------------------------------------------- agg1 + relu + gemm2 fused
// h1 row lives in registers (one float/lane); gemm2 via 64 shfl broadcasts,
// same ascending-k fmaf order as the standalone gemm2 -> bit-identical xw2.
__global__ __launch_bounds__(256) void agg_gemm2_kernel(const float* __restrict__ xw,
                                                        const int* __restrict__ nbr,
                                                        const float* __restrict__ ew,
                                                        const float* __restrict__ dis,
                                                        const float* __restrict__ b,
                                                        const int* __restrict__ sid,
                                                        const float* __restrict__ w2,
                                                        float* __restrict__ xw2) {
  int wv = threadIdx.x >> 6, lane = threadIdx.x & 63;
  int i = sid[(blockIdx.x << 2) + wv];
  float di = dis[i];
  float acc = 0.0f;
#pragma unroll 4
  for (int k = 0; k < KK; ++k) {
    int s = nbr[i*KK + k];
    float coef = (dis[s] * ew[i*KK + k]) * di;   // (dis[s]*w)*dis[t]
    acc = fmaf(coef, xw[s*HH + lane], acc);
  }
  acc = fmaf(di * di, xw[i*HH + lane], acc);     // self loop last
  float hv = fmaxf(acc + b[lane], 0.0f);         // h1[i][lane]
  float acc2 = 0.0f;
#pragma unroll 16
  for (int k = 0; k < HH; ++k) {
    float hk = __shfl(hv, k, 64);
    acc2 = fmaf(hk, w2[k*HH + lane], acc2);
  }
  xw2[i*HH + lane] = acc2;
}

// ---------------------------------------------------------------- agg2 + relu + fc (final)
__global__ __launch_bounds__(256) void agg_fc_kernel(const float* __restrict__ xw,
                                                     const int* __restrict__ nbr,
                                                     const float* __restrict__ ew,
                                                     const float* __restrict__ dis,
                                                     const float* __restrict__ b,
                                                     const float* __restrict__ wfc,
                                                     const float* __restrict__ bfc,
                                                     const int* __restrict__ sid,
                                                     float* __restrict__ out) {
  int wv = threadIdx.x >> 6, lane = threadIdx.x & 63;
  int i = sid[(blockIdx.x << 2) + wv];
  float di = dis[i];
  float acc = 0.0f;
#pragma unroll 4
  for (int k = 0; k < KK; ++k) {
    int s = nbr[i*KK + k];
    float coef = (dis[s] * ew[i*KK + k]) * di;
    acc = fmaf(coef, xw[s*HH + lane], acc);
  }
  acc = fmaf(di * di, xw[i*HH + lane], acc);
  float v = fmaxf(acc + b[lane], 0.0f);             // h2 feature
  float p = v * wfc[lane];                          // h2 @ Wfc  (F_OUT = 1)
#pragma unroll
  for (int off = 32; off > 0; off >>= 1) p = p + __shfl_xor(p, off, 64);
  if (lane == 0) out[i] = p + bfc[0];
}

// ---------------------------------------------------------------- launch
extern "C" void kernel_launch(void* const* d_in, const int* in_sizes, int n_in,
                              void* d_out, int out_size, void* d_ws, size_t ws_size,
                              hipStream_t stream) {
  (void)in_sizes; (void)n_in; (void)out_size; (void)ws_size;
  const float* x   = (const float*)d_in[0];
  const float* c   = (const float*)d_in[1];
  const float* W1  = (const float*)d_in[2];
  const float* b1  = (const float*)d_in[3];
  const float* W2  = (const float*)d_in[4];
  const float* b2  = (const float*)d_in[5];
  const float* Wfc = (const float*)d_in[6];
  const float* bfc = (const float*)d_in[7];
  float* out = (float*)d_out;

  char* ws = (char*)d_ws;
  size_t off = 0;
  auto alloc = [&](size_t bytes) -> void* {
    void* p = ws + off;
    off += (bytes + 255) & ~size_t(255);
    return p;
  };
  float4*   pack   = (float4*)  alloc(NN * sizeof(float4));       // 256 KB
  float4*   sorted = (float4*)  alloc(NN * sizeof(float4));       // 256 KB
  unsigned* cnt    = (unsigned*)alloc(NCELL * sizeof(unsigned));  // 16 KB
  unsigned* cstart = (unsigned*)alloc((NCELL+1) * sizeof(unsigned));
  unsigned* cursor = (unsigned*)alloc(NCELL * sizeof(unsigned));
  unsigned* cellid = (unsigned*)alloc(NN * sizeof(unsigned));     // 64 KB
  int*      sid    = (int*)     alloc(NN * sizeof(int));          // 64 KB
  int*      nbr    = (int*)     alloc(NE * sizeof(int));          // 1 MB
  float*    ew     = (float*)   alloc(NE * sizeof(float));        // 1 MB (d then ew in-place)
  float*    dis    = (float*)   alloc(NN * sizeof(float));        // 64 KB
  unsigned* gmm    = (unsigned*)alloc(2 * sizeof(unsigned));
  float*    xw1    = (float*)   alloc(NN * HH * sizeof(float));   // 4 MB
  float*    xw2    = (float*)   alloc(NN * HH * sizeof(float));   // 4 MB

  const int NB = (NN + 255) / 256;
  hipMemsetAsync(cnt, 0, NCELL * sizeof(unsigned), stream);
  prep_count_kernel<<<NB,   256, 0, stream>>>(c, pack, cellid, cnt, gmm);
  scan_kernel      <<<1,   1024, 0, stream>>>(cnt, cstart, cursor);
  scatter_kernel   <<<NB,   256, 0, stream>>>(pack, cellid, cursor, sorted, sid);
  gemm1_kernel     <<<NN*16/256, 256, 0, stream>>>(x, W1, xw1);
  knn_kernel       <<<NCELL/4,    64, 0, stream>>>(sorted, cstart, c, nbr, ew, gmm);
  ewdeg_kernel     <<<NB,   256, 0, stream>>>(gmm, ew, dis);
  agg_gemm2_kernel <<<NN/4, 256, 0, stream>>>(xw1, nbr, ew, dis, b1, sid, W2, xw2);
  agg_fc_kernel    <<<NN/4, 256, 0, stream>>>(xw2, nbr, ew, dis, b2, Wfc, bfc, sid, out);
}